// Round 5
// baseline (643.762 us; speedup 1.0000x reference)
//
#include <hip/hip_runtime.h>

#define BB 16384
#define TT 50
#define EMBD 16
#define NSP 8
#define NDD 8
#define VV 100000
#define DNN 184
#define NEGINF (-4294967295.0f)

__device__ __forceinline__ float sigmoidf_(float x) { return 1.0f / (1.0f + __expf(-x)); }

// ---------------- K1: per-b fused (gathers + DIN + GRU) -> dnn_input[B,184] ----------------
__global__ __launch_bounds__(64) void k1_fused(
    const float* __restrict__ dense,
    const float* __restrict__ tables,
    const float* __restrict__ seq_table,
    const float* __restrict__ aw1, const float* __restrict__ ab1,
    const float* __restrict__ aw2, const float* __restrict__ ab2,
    const float* __restrict__ aw3, const float* __restrict__ ab3,
    const float* __restrict__ gW, const float* __restrict__ gU, const float* __restrict__ gB,
    const int* __restrict__ sparse_in, const int* __restrict__ seq_in, const int* __restrict__ hist_in,
    float* __restrict__ dnn_out)
{
    const int b = blockIdx.x;
    const int lane = threadIdx.x;

    __shared__ float hist[64][EMBD + 1];   // [t][0..15]=emb, [16]=mask; rows >=T zeroed
    __shared__ float q_sh[EMBD];
    __shared__ float dnn[DNN];
    __shared__ float wsoft[64];
    __shared__ float red[64];
    __shared__ float recs[48];
    __shared__ float xal[48];
    __shared__ float hgru[EMBD];

    // ---- gather history embeddings + mask
    if (lane < TT) {
        int hidx = hist_in[b * TT + lane];
        const float4* src = (const float4*)(tables + (size_t)hidx * EMBD);
        float4 a0 = src[0], a1 = src[1], a2 = src[2], a3 = src[3];
        hist[lane][0] = a0.x;  hist[lane][1] = a0.y;  hist[lane][2] = a0.z;  hist[lane][3] = a0.w;
        hist[lane][4] = a1.x;  hist[lane][5] = a1.y;  hist[lane][6] = a1.z;  hist[lane][7] = a1.w;
        hist[lane][8] = a2.x;  hist[lane][9] = a2.y;  hist[lane][10] = a2.z; hist[lane][11] = a2.w;
        hist[lane][12] = a3.x; hist[lane][13] = a3.y; hist[lane][14] = a3.z; hist[lane][15] = a3.w;
        hist[lane][16] = (hidx != 0) ? 1.0f : 0.0f;
    } else {
        #pragma unroll
        for (int j = 0; j <= EMBD; ++j) hist[lane][j] = 0.0f;
    }
    // target embedding (table 0, sparse slot 0)
    if (lane < EMBD) {
        int ti = sparse_in[b * NSP];
        q_sh[lane] = tables[(size_t)ti * EMBD + lane];
    }
    // dense -> dnn[0..7]
    if (lane < NDD) dnn[lane] = dense[b * NDD + lane];
    // sparse flat -> dnn[8..135]
    for (int i = lane; i < NSP * EMBD; i += 64) {
        int s = i >> 4, j = i & 15;
        int idx = sparse_in[b * NSP + s];
        dnn[NDD + i] = tables[((size_t)s * VV + idx) * EMBD + j];
    }
    // seq mean partial sums (4 groups x 16 emb lanes)
    {
        int g = lane >> 4, j = lane & 15;
        float acc = 0.0f;
        for (int t = g; t < TT; t += 4) {
            int idx = seq_in[b * TT + t];
            acc += seq_table[(size_t)idx * EMBD + j];
        }
        red[lane] = acc;
    }
    __syncthreads();
    if (lane < EMBD)
        dnn[NDD + NSP * EMBD + lane] =
            (red[lane] + red[16 + lane] + red[32 + lane] + red[48 + lane]) * (1.0f / TT);

    // ---- DIN attention: lane = timestep t ----
    float q[EMBD], k[EMBD];
    #pragma unroll
    for (int j = 0; j < EMBD; ++j) { q[j] = q_sh[j]; k[j] = hist[lane][j]; }
    float mask = hist[lane][16];

    float h2a[32];
    #pragma unroll
    for (int i = 0; i < 32; ++i) h2a[i] = ab2[i];

    for (int c = 0; c < 4; ++c) {            // h1 in chunks of 16 units
        float h1c[16];
        #pragma unroll
        for (int jj = 0; jj < 16; ++jj) h1c[jj] = ab1[c * 16 + jj];
        #pragma unroll 4
        for (int j = 0; j < 16; ++j) {
            float qa = q[j], ka = k[j];
            float qmk = qa - ka, qk = qa * ka;
            const float* r0 = aw1 + j * 64 + c * 16;          // rows: q part
            const float* r1 = r0 + 16 * 64;                   // k part
            const float* r2 = r0 + 32 * 64;                   // q-k part
            const float* r3 = r0 + 48 * 64;                   // q*k part
            #pragma unroll
            for (int jj = 0; jj < 16; ++jj)
                h1c[jj] += qa * r0[jj] + ka * r1[jj] + qmk * r2[jj] + qk * r3[jj];
        }
        #pragma unroll 4
        for (int jj = 0; jj < 16; ++jj) {
            float hv = fmaxf(h1c[jj], 0.0f);
            const float* w2r = aw2 + (c * 16 + jj) * 32;
            #pragma unroll
            for (int i = 0; i < 32; ++i) h2a[i] += hv * w2r[i];
        }
    }
    float score = ab3[0];
    #pragma unroll
    for (int i = 0; i < 32; ++i) score += fmaxf(h2a[i], 0.0f) * aw3[i];

    score = (lane < TT && mask > 0.0f) ? score : NEGINF;
    float m = score;
    #pragma unroll
    for (int off = 32; off > 0; off >>= 1) m = fmaxf(m, __shfl_xor(m, off));
    float e = (lane < TT) ? __expf(score - m) : 0.0f;
    float ssum = e;
    #pragma unroll
    for (int off = 32; off > 0; off >>= 1) ssum += __shfl_xor(ssum, off);
    wsoft[lane] = e / ssum;
    __syncthreads();
    if (lane < EMBD) {
        float acc = 0.0f;
        for (int t = 0; t < TT; ++t) acc += wsoft[t] * hist[t][lane];
        dnn[NDD + NSP * EMBD + EMBD + lane] = acc;   // din_out -> dnn[152..167]
    }

    // ---- GRU (reset_after): lanes 0..47 own gate units ----
    float Wc[EMBD], Uc[EMBD], bi = 0.0f, br = 0.0f;
    if (lane < 48) {
        #pragma unroll
        for (int v = 0; v < EMBD; ++v) { Wc[v] = gW[v * 48 + lane]; Uc[v] = gU[v * 48 + lane]; }
        bi = gB[lane]; br = gB[48 + lane];
    }
    if (lane < EMBD) hgru[lane] = 0.0f;
    __syncthreads();
    for (int t = 0; t < TT; ++t) {
        if (lane < 48) {
            float xa = bi, rc = br;
            #pragma unroll
            for (int v = 0; v < EMBD; ++v) {
                xa += hist[t][v] * Wc[v];
                rc += hgru[v] * Uc[v];
            }
            xal[lane] = xa; recs[lane] = rc;
        }
        __syncthreads();
        if (lane < EMBD) {
            float z  = sigmoidf_(xal[lane] + recs[lane]);
            float r  = sigmoidf_(xal[16 + lane] + recs[16 + lane]);
            float hh = tanhf(xal[32 + lane] + r * recs[32 + lane]);
            float hold = hgru[lane];
            float hnew = z * hold + (1.0f - z) * hh;
            hgru[lane] = (hist[t][16] > 0.0f) ? hnew : hold;
        }
        __syncthreads();
    }
    if (lane < EMBD) dnn[DNN - EMBD + lane] = hgru[lane];   // gru_out -> dnn[168..183]
    __syncthreads();

    for (int i = lane; i < DNN; i += 64)
        dnn_out[(size_t)b * DNN + i] = dnn[i];
}

// ---------------- K2: MMOE + gates + heads, 16 batch rows per block ----------------
__global__ __launch_bounds__(256) void k2_mmoe(
    const float* __restrict__ dnn_in,
    const float* __restrict__ ew1, const float* __restrict__ eb1,
    const float* __restrict__ ew2, const float* __restrict__ eb2,
    const float* __restrict__ gfw, const float* __restrict__ gfb,
    const float* __restrict__ glw, const float* __restrict__ glb,
    const float* __restrict__ fw, const float* __restrict__ fb,
    const float* __restrict__ lw, const float* __restrict__ lb,
    float* __restrict__ out)
{
    const int tid = threadIdx.x;
    const int b0 = blockIdx.x * 16;

    __shared__ float dlds[16 * DNN];  // 16 dnn rows, 11776 B
    __shared__ float h1L[16][512];    // [bb][e*128+i]
    __shared__ float h2L[16][256];    // [bb][e*64+i]
    __shared__ float gateL[16][8];    // [bb][f:0..3, l:4..7]

    // stage 16 contiguous dnn rows into LDS (coalesced: 2944 floats)
    {
        const float* drow = dnn_in + (size_t)b0 * DNN;
        for (int i = tid; i < 16 * DNN; i += 256) dlds[i] = drow[i];
    }
    __syncthreads();

    // h1: 512 cols, 2 per thread; dnn via float4 LDS reads, weights coalesced global
    for (int cc = 0; cc < 2; ++cc) {
        int col = tid + cc * 256;
        int eidx = col >> 7, i = col & 127;
        const float* w = ew1 + (size_t)eidx * DNN * 128 + i;
        float acc[16];
        float bias = eb1[col];
        #pragma unroll
        for (int bb = 0; bb < 16; ++bb) acc[bb] = bias;
        for (int d = 0; d < DNN; d += 4) {
            float w0 = w[(size_t)(d + 0) * 128];
            float w1v = w[(size_t)(d + 1) * 128];
            float w2v = w[(size_t)(d + 2) * 128];
            float w3v = w[(size_t)(d + 3) * 128];
            #pragma unroll
            for (int bb = 0; bb < 16; ++bb) {
                const float4 h4 = *(const float4*)&dlds[bb * DNN + d];
                acc[bb] += h4.x * w0 + h4.y * w1v + h4.z * w2v + h4.w * w3v;
            }
        }
        #pragma unroll
        for (int bb = 0; bb < 16; ++bb) h1L[bb][col] = fmaxf(acc[bb], 0.0f);
    }

    // gate logits (independent of h1)
    if (tid < 128) {
        int bb = tid >> 3, which = (tid >> 2) & 1, eidx = tid & 3;
        const float* gw = which ? glw : gfw;
        float acc = which ? glb[eidx] : gfb[eidx];
        for (int d = 0; d < DNN; ++d) acc += dlds[bb * DNN + d] * gw[d * 4 + eidx];
        gateL[bb][which * 4 + eidx] = acc;
    }
    __syncthreads();

    // softmax over experts
    if (tid < 32) {
        int bb = tid >> 1, which = tid & 1;
        float l0 = gateL[bb][which * 4 + 0], l1 = gateL[bb][which * 4 + 1];
        float l2 = gateL[bb][which * 4 + 2], l3 = gateL[bb][which * 4 + 3];
        float mm = fmaxf(fmaxf(l0, l1), fmaxf(l2, l3));
        float e0 = __expf(l0 - mm), e1 = __expf(l1 - mm), e2 = __expf(l2 - mm), e3 = __expf(l3 - mm);
        float ss = e0 + e1 + e2 + e3;
        gateL[bb][which * 4 + 0] = e0 / ss; gateL[bb][which * 4 + 1] = e1 / ss;
        gateL[bb][which * 4 + 2] = e2 / ss; gateL[bb][which * 4 + 3] = e3 / ss;
    }

    // h2: 256 cols, 1 per thread; h1 via broadcast LDS float4 reads
    {
        int col = tid;
        int eidx = col >> 6, i = col & 63;
        const float* w = ew2 + (size_t)eidx * 128 * 64 + i;
        float acc[16];
        float bias = eb2[col];
        #pragma unroll
        for (int bb = 0; bb < 16; ++bb) acc[bb] = bias;
        for (int d = 0; d < 128; d += 4) {
            float w0 = w[d * 64], w1v = w[(d + 1) * 64], w2v = w[(d + 2) * 64], w3v = w[(d + 3) * 64];
            #pragma unroll
            for (int bb = 0; bb < 16; ++bb) {
                const float4 h4 = *(const float4*)&h1L[bb][eidx * 128 + d];
                acc[bb] += h4.x * w0 + h4.y * w1v + h4.z * w2v + h4.w * w3v;
            }
        }
        #pragma unroll
        for (int bb = 0; bb < 16; ++bb) h2L[bb][col] = fmaxf(acc[bb], 0.0f);
    }
    __syncthreads();

    // heads: wave w handles 4 batch rows; lane = output unit o
    {
        int wv = tid >> 6, lane = tid & 63;
        for (int it = 0; it < 4; ++it) {
            int bb = wv * 4 + it;
            float h0 = h2L[bb][lane], h1v = h2L[bb][64 + lane], h2v = h2L[bb][128 + lane], h3v = h2L[bb][192 + lane];
            float fin = gateL[bb][0] * h0 + gateL[bb][1] * h1v + gateL[bb][2] * h2v + gateL[bb][3] * h3v;
            float lik = gateL[bb][4] * h0 + gateL[bb][5] * h1v + gateL[bb][6] * h2v + gateL[bb][7] * h3v;
            float pf = fin * fw[lane];
            float pl = lik * lw[lane];
            #pragma unroll
            for (int off = 32; off > 0; off >>= 1) {
                pf += __shfl_xor(pf, off);
                pl += __shfl_xor(pl, off);
            }
            if (lane == 0) {
                out[b0 + bb]      = sigmoidf_(pf + fb[0]);
                out[BB + b0 + bb] = sigmoidf_(pl + lb[0]);
            }
        }
    }
}

extern "C" void kernel_launch(void* const* d_in, const int* in_sizes, int n_in,
                              void* d_out, int out_size, void* d_ws, size_t ws_size,
                              hipStream_t stream)
{
    const float* dense     = (const float*)d_in[0];
    const float* tables    = (const float*)d_in[1];
    const float* seq_table = (const float*)d_in[2];
    const float* aw1 = (const float*)d_in[3];  const float* ab1 = (const float*)d_in[4];
    const float* aw2 = (const float*)d_in[5];  const float* ab2 = (const float*)d_in[6];
    const float* aw3 = (const float*)d_in[7];  const float* ab3 = (const float*)d_in[8];
    const float* gW  = (const float*)d_in[9];  const float* gU  = (const float*)d_in[10];
    const float* gB  = (const float*)d_in[11];
    const float* ew1 = (const float*)d_in[12]; const float* eb1 = (const float*)d_in[13];
    const float* ew2 = (const float*)d_in[14]; const float* eb2 = (const float*)d_in[15];
    const float* gfw = (const float*)d_in[16]; const float* gfb = (const float*)d_in[17];
    const float* glw = (const float*)d_in[18]; const float* glb = (const float*)d_in[19];
    const float* fw  = (const float*)d_in[20]; const float* fb  = (const float*)d_in[21];
    const float* lw  = (const float*)d_in[22]; const float* lb  = (const float*)d_in[23];
    const int* sparse_in = (const int*)d_in[24];
    const int* seq_in    = (const int*)d_in[25];
    const int* hist_in   = (const int*)d_in[26];
    float* out = (float*)d_out;
    float* dnn_ws = (float*)d_ws;   // B*184 floats = 12.06 MB

    hipLaunchKernelGGL(k1_fused, dim3(BB), dim3(64), 0, stream,
                       dense, tables, seq_table, aw1, ab1, aw2, ab2, aw3, ab3,
                       gW, gU, gB, sparse_in, seq_in, hist_in, dnn_ws);
    hipLaunchKernelGGL(k2_mmoe, dim3(BB / 16), dim3(256), 0, stream,
                       dnn_ws, ew1, eb1, ew2, eb2, gfw, gfb, glw, glb,
                       fw, fb, lw, lb, out);
}

// Round 6
// 582.795 us; speedup vs baseline: 1.1046x; 1.1046x over previous
//
#include <hip/hip_runtime.h>

#define BB 16384
#define TT 50
#define EMBD 16
#define NSP 8
#define NDD 8
#define VV 100000
#define DNN 184
#define NEGINF (-4294967295.0f)

__device__ __forceinline__ float sigmoidf_(float x) { return 1.0f / (1.0f + __expf(-x)); }
// tanh(x) = 1 - 2/(e^{2x}+1); correct limits at +/-inf
__device__ __forceinline__ float tanhf_(float x) { return 1.0f - 2.0f / (__expf(2.0f * x) + 1.0f); }

// ---------------- K1: 4 waves/block, wave w owns b = blockIdx*4+w ----------------
__global__ __launch_bounds__(256, 5) void k1_fused(
    const float* __restrict__ dense,
    const float* __restrict__ tables,
    const float* __restrict__ seq_table,
    const float* __restrict__ aw1, const float* __restrict__ ab1,
    const float* __restrict__ aw2, const float* __restrict__ ab2,
    const float* __restrict__ aw3, const float* __restrict__ ab3,
    const float* __restrict__ gW, const float* __restrict__ gU, const float* __restrict__ gB,
    const int* __restrict__ sparse_in, const int* __restrict__ seq_in, const int* __restrict__ hist_in,
    float* __restrict__ dnn_out)
{
    const int w = threadIdx.x >> 6;
    const int lane = threadIdx.x & 63;
    const int b = blockIdx.x * 4 + w;

    __shared__ float histE[4][64][16];   // 16 KB  (row = 64B aligned for b128)
    __shared__ float maskL[4][64];       // 1 KB
    __shared__ float qsh[4][16];
    __shared__ float dnnL[4][DNN];       // ~2.9 KB
    __shared__ float wsoft[4][64];       // 1 KB

    // ---- staging ----
    if (lane < TT) {
        int hidx = hist_in[b * TT + lane];
        const float4* src = (const float4*)(tables + (size_t)hidx * EMBD);
        float4 a0 = src[0], a1 = src[1], a2 = src[2], a3 = src[3];
        *(float4*)&histE[w][lane][0]  = a0;
        *(float4*)&histE[w][lane][4]  = a1;
        *(float4*)&histE[w][lane][8]  = a2;
        *(float4*)&histE[w][lane][12] = a3;
        maskL[w][lane] = (hidx != 0) ? 1.0f : 0.0f;
    } else {
        float4 z = make_float4(0.f, 0.f, 0.f, 0.f);
        *(float4*)&histE[w][lane][0]  = z;
        *(float4*)&histE[w][lane][4]  = z;
        *(float4*)&histE[w][lane][8]  = z;
        *(float4*)&histE[w][lane][12] = z;
        maskL[w][lane] = 0.0f;
    }
    if (lane < EMBD) {
        int ti = sparse_in[b * NSP];
        qsh[w][lane] = tables[(size_t)ti * EMBD + lane];
    }
    if (lane < NDD) dnnL[w][lane] = dense[b * NDD + lane];
    for (int i = lane; i < NSP * EMBD; i += 64) {
        int s = i >> 4, j = i & 15;
        int idx = sparse_in[b * NSP + s];
        dnnL[w][NDD + i] = tables[((size_t)s * VV + idx) * EMBD + j];
    }
    // seq mean: 4 t-groups x 16 emb lanes, combine via shfl_xor
    {
        int g = lane >> 4, j = lane & 15;
        float acc = 0.0f;
        for (int t = g; t < TT; t += 4) {
            int idx = seq_in[b * TT + t];
            acc += seq_table[(size_t)idx * EMBD + j];
        }
        acc += __shfl_xor(acc, 16);
        acc += __shfl_xor(acc, 32);
        if (lane < EMBD) dnnL[w][NDD + NSP * EMBD + lane] = acc * (1.0f / TT);
    }
    __syncthreads();

    // ---- DIN attention: lane = timestep t ----
    float q[EMBD], k[EMBD];
    {
        float4 q0 = *(const float4*)&qsh[w][0],  q1 = *(const float4*)&qsh[w][4];
        float4 q2 = *(const float4*)&qsh[w][8],  q3 = *(const float4*)&qsh[w][12];
        q[0]=q0.x; q[1]=q0.y; q[2]=q0.z; q[3]=q0.w; q[4]=q1.x; q[5]=q1.y; q[6]=q1.z; q[7]=q1.w;
        q[8]=q2.x; q[9]=q2.y; q[10]=q2.z; q[11]=q2.w; q[12]=q3.x; q[13]=q3.y; q[14]=q3.z; q[15]=q3.w;
        float4 k0 = *(const float4*)&histE[w][lane][0],  k1 = *(const float4*)&histE[w][lane][4];
        float4 k2 = *(const float4*)&histE[w][lane][8],  k3 = *(const float4*)&histE[w][lane][12];
        k[0]=k0.x; k[1]=k0.y; k[2]=k0.z; k[3]=k0.w; k[4]=k1.x; k[5]=k1.y; k[6]=k1.z; k[7]=k1.w;
        k[8]=k2.x; k[9]=k2.y; k[10]=k2.z; k[11]=k2.w; k[12]=k3.x; k[13]=k3.y; k[14]=k3.z; k[15]=k3.w;
    }
    float mask = maskL[w][lane];

    float h2a[32];
    #pragma unroll
    for (int i = 0; i < 32; ++i) h2a[i] = ab2[i];

    for (int c = 0; c < 4; ++c) {
        float h1c[16];
        #pragma unroll
        for (int jj = 0; jj < 16; ++jj) h1c[jj] = ab1[c * 16 + jj];
        #pragma unroll 4
        for (int j = 0; j < 16; ++j) {
            float qa = q[j], ka = k[j];
            float qmk = qa - ka, qk = qa * ka;
            const float* r0 = aw1 + j * 64 + c * 16;
            const float* r1 = r0 + 16 * 64;
            const float* r2 = r0 + 32 * 64;
            const float* r3 = r0 + 48 * 64;
            #pragma unroll
            for (int jj = 0; jj < 16; ++jj)
                h1c[jj] += qa * r0[jj] + ka * r1[jj] + qmk * r2[jj] + qk * r3[jj];
        }
        #pragma unroll 4
        for (int jj = 0; jj < 16; ++jj) {
            float hv = fmaxf(h1c[jj], 0.0f);
            const float* w2r = aw2 + (c * 16 + jj) * 32;
            #pragma unroll
            for (int i = 0; i < 32; ++i) h2a[i] += hv * w2r[i];
        }
    }
    float score = ab3[0];
    #pragma unroll
    for (int i = 0; i < 32; ++i) score += fmaxf(h2a[i], 0.0f) * aw3[i];

    score = (lane < TT && mask > 0.0f) ? score : NEGINF;
    float m = score;
    #pragma unroll
    for (int off = 32; off > 0; off >>= 1) m = fmaxf(m, __shfl_xor(m, off));
    float e = (lane < TT) ? __expf(score - m) : 0.0f;
    float ssum = e;
    #pragma unroll
    for (int off = 32; off > 0; off >>= 1) ssum += __shfl_xor(ssum, off);
    wsoft[w][lane] = e / ssum;
    __syncthreads();
    if (lane < EMBD) {
        float acc = 0.0f;
        for (int t = 0; t < TT; ++t) acc += wsoft[w][t] * histE[w][t][lane];
        dnnL[w][NDD + NSP * EMBD + EMBD + lane] = acc;   // din_out -> [152..167]
    }

    // ---- GRU: barrier-free, h state in lanes 0..15, units on lanes 0..47 ----
    float Wc[EMBD], Uc[EMBD], bi = 0.0f, br = 0.0f;
    if (lane < 48) {
        #pragma unroll
        for (int v = 0; v < EMBD; ++v) { Wc[v] = gW[v * 48 + lane]; Uc[v] = gU[v * 48 + lane]; }
        bi = gB[lane]; br = gB[48 + lane];
    }
    float hcur = 0.0f;
    for (int t = 0; t < TT; ++t) {
        // hist row t (uniform address -> LDS broadcast)
        float4 x0 = *(const float4*)&histE[w][t][0];
        float4 x1 = *(const float4*)&histE[w][t][4];
        float4 x2 = *(const float4*)&histE[w][t][8];
        float4 x3 = *(const float4*)&histE[w][t][12];
        float mt = maskL[w][t];
        // broadcast previous h from lanes 0..15
        float hv[16];
        #pragma unroll
        for (int v = 0; v < 16; ++v) hv[v] = __shfl(hcur, v);
        float xa = bi, rc = br;
        xa += x0.x*Wc[0] + x0.y*Wc[1] + x0.z*Wc[2] + x0.w*Wc[3];
        xa += x1.x*Wc[4] + x1.y*Wc[5] + x1.z*Wc[6] + x1.w*Wc[7];
        xa += x2.x*Wc[8] + x2.y*Wc[9] + x2.z*Wc[10] + x2.w*Wc[11];
        xa += x3.x*Wc[12] + x3.y*Wc[13] + x3.z*Wc[14] + x3.w*Wc[15];
        #pragma unroll
        for (int v = 0; v < 16; ++v) rc += hv[v] * Uc[v];
        // gate swaps: unit u<16 needs (u+16) and (u+32) parts
        float xr = __shfl(xa, lane + 16), xh = __shfl(xa, lane + 32);
        float rr = __shfl(rc, lane + 16), rh = __shfl(rc, lane + 32);
        float z  = sigmoidf_(xa + rc);          // lanes 0..15: z-gate
        float r  = sigmoidf_(xr + rr);
        float hh = tanhf_(xh + r * rh);
        float hnew = z * hcur + (1.0f - z) * hh;
        hcur = (mt > 0.0f) ? hnew : hcur;       // meaningful on lanes 0..15 only
    }
    if (lane < EMBD) dnnL[w][DNN - EMBD + lane] = hcur;   // gru_out -> [168..183]
    __syncthreads();

    for (int i = lane; i < DNN; i += 64)
        dnn_out[(size_t)b * DNN + i] = dnnL[w][i];
}

// ---------------- K2: MMOE + gates + heads, 8 batch rows per block ----------------
#define BBT 8
__global__ __launch_bounds__(256) void k2_mmoe(
    const float* __restrict__ dnn_in,
    const float* __restrict__ ew1, const float* __restrict__ eb1,
    const float* __restrict__ ew2, const float* __restrict__ eb2,
    const float* __restrict__ gfw, const float* __restrict__ gfb,
    const float* __restrict__ glw, const float* __restrict__ glb,
    const float* __restrict__ fw, const float* __restrict__ fb,
    const float* __restrict__ lw, const float* __restrict__ lb,
    float* __restrict__ out)
{
    const int tid = threadIdx.x;
    const int b0 = blockIdx.x * BBT;

    __shared__ float dlds[BBT * DNN];   // 5.75 KB
    __shared__ float h1L[BBT][512];     // 16 KB
    __shared__ float h2L[BBT][256];     // 8 KB
    __shared__ float gateL[BBT][8];

    {
        const float* drow = dnn_in + (size_t)b0 * DNN;
        for (int i = tid; i < BBT * DNN; i += 256) dlds[i] = drow[i];
    }
    __syncthreads();

    // h1: thread owns cols tid and tid+256, one fused d-loop (halves LDS reads)
    {
        int col0 = tid;
        int e0 = col0 >> 7, i0 = col0 & 127;
        const float* wp0 = ew1 + (size_t)e0 * DNN * 128 + i0;
        const float* wp1 = ew1 + (size_t)(e0 + 2) * DNN * 128 + i0;
        float acc0[BBT], acc1[BBT];
        float bias0 = eb1[col0], bias1 = eb1[col0 + 256];
        #pragma unroll
        for (int bb = 0; bb < BBT; ++bb) { acc0[bb] = bias0; acc1[bb] = bias1; }
        for (int d = 0; d < DNN; d += 4) {
            float w00 = wp0[(size_t)(d + 0) * 128], w01 = wp0[(size_t)(d + 1) * 128];
            float w02 = wp0[(size_t)(d + 2) * 128], w03 = wp0[(size_t)(d + 3) * 128];
            float w10 = wp1[(size_t)(d + 0) * 128], w11 = wp1[(size_t)(d + 1) * 128];
            float w12 = wp1[(size_t)(d + 2) * 128], w13 = wp1[(size_t)(d + 3) * 128];
            #pragma unroll
            for (int bb = 0; bb < BBT; ++bb) {
                const float4 h4 = *(const float4*)&dlds[bb * DNN + d];
                acc0[bb] += h4.x * w00 + h4.y * w01 + h4.z * w02 + h4.w * w03;
                acc1[bb] += h4.x * w10 + h4.y * w11 + h4.z * w12 + h4.w * w13;
            }
        }
        #pragma unroll
        for (int bb = 0; bb < BBT; ++bb) {
            h1L[bb][col0]       = fmaxf(acc0[bb], 0.0f);
            h1L[bb][col0 + 256] = fmaxf(acc1[bb], 0.0f);
        }
    }

    // gate logits (8 rows x 2 gates x 4 experts = 64 threads)
    if (tid < 64) {
        int bb = tid >> 3, which = (tid >> 2) & 1, eidx = tid & 3;
        const float* gw = which ? glw : gfw;
        float acc = which ? glb[eidx] : gfb[eidx];
        for (int d = 0; d < DNN; ++d) acc += dlds[bb * DNN + d] * gw[d * 4 + eidx];
        gateL[bb][which * 4 + eidx] = acc;
    }
    __syncthreads();

    // softmax over experts
    if (tid < 16) {
        int bb = tid >> 1, which = tid & 1;
        float l0 = gateL[bb][which * 4 + 0], l1 = gateL[bb][which * 4 + 1];
        float l2 = gateL[bb][which * 4 + 2], l3 = gateL[bb][which * 4 + 3];
        float mm = fmaxf(fmaxf(l0, l1), fmaxf(l2, l3));
        float e0 = __expf(l0 - mm), e1 = __expf(l1 - mm), e2 = __expf(l2 - mm), e3 = __expf(l3 - mm);
        float ss = e0 + e1 + e2 + e3;
        gateL[bb][which * 4 + 0] = e0 / ss; gateL[bb][which * 4 + 1] = e1 / ss;
        gateL[bb][which * 4 + 2] = e2 / ss; gateL[bb][which * 4 + 3] = e3 / ss;
    }

    // h2: 256 cols, 1 per thread
    {
        int col = tid;
        int eidx = col >> 6, i = col & 63;
        const float* wp = ew2 + (size_t)eidx * 128 * 64 + i;
        float acc[BBT];
        float bias = eb2[col];
        #pragma unroll
        for (int bb = 0; bb < BBT; ++bb) acc[bb] = bias;
        for (int d = 0; d < 128; d += 4) {
            float w0 = wp[(d + 0) * 64], w1v = wp[(d + 1) * 64];
            float w2v = wp[(d + 2) * 64], w3v = wp[(d + 3) * 64];
            #pragma unroll
            for (int bb = 0; bb < BBT; ++bb) {
                const float4 h4 = *(const float4*)&h1L[bb][eidx * 128 + d];
                acc[bb] += h4.x * w0 + h4.y * w1v + h4.z * w2v + h4.w * w3v;
            }
        }
        #pragma unroll
        for (int bb = 0; bb < BBT; ++bb) h2L[bb][col] = fmaxf(acc[bb], 0.0f);
    }
    __syncthreads();

    // heads: wave wv handles 2 batch rows; lane = h2 unit
    {
        int wv = tid >> 6, lane = tid & 63;
        for (int it = 0; it < 2; ++it) {
            int bb = wv * 2 + it;
            float h0 = h2L[bb][lane], h1v = h2L[bb][64 + lane];
            float h2v = h2L[bb][128 + lane], h3v = h2L[bb][192 + lane];
            float fin = gateL[bb][0] * h0 + gateL[bb][1] * h1v + gateL[bb][2] * h2v + gateL[bb][3] * h3v;
            float lik = gateL[bb][4] * h0 + gateL[bb][5] * h1v + gateL[bb][6] * h2v + gateL[bb][7] * h3v;
            float pf = fin * fw[lane];
            float pl = lik * lw[lane];
            #pragma unroll
            for (int off = 32; off > 0; off >>= 1) {
                pf += __shfl_xor(pf, off);
                pl += __shfl_xor(pl, off);
            }
            if (lane == 0) {
                out[b0 + bb]      = sigmoidf_(pf + fb[0]);
                out[BB + b0 + bb] = sigmoidf_(pl + lb[0]);
            }
        }
    }
}

extern "C" void kernel_launch(void* const* d_in, const int* in_sizes, int n_in,
                              void* d_out, int out_size, void* d_ws, size_t ws_size,
                              hipStream_t stream)
{
    const float* dense     = (const float*)d_in[0];
    const float* tables    = (const float*)d_in[1];
    const float* seq_table = (const float*)d_in[2];
    const float* aw1 = (const float*)d_in[3];  const float* ab1 = (const float*)d_in[4];
    const float* aw2 = (const float*)d_in[5];  const float* ab2 = (const float*)d_in[6];
    const float* aw3 = (const float*)d_in[7];  const float* ab3 = (const float*)d_in[8];
    const float* gW  = (const float*)d_in[9];  const float* gU  = (const float*)d_in[10];
    const float* gB  = (const float*)d_in[11];
    const float* ew1 = (const float*)d_in[12]; const float* eb1 = (const float*)d_in[13];
    const float* ew2 = (const float*)d_in[14]; const float* eb2 = (const float*)d_in[15];
    const float* gfw = (const float*)d_in[16]; const float* gfb = (const float*)d_in[17];
    const float* glw = (const float*)d_in[18]; const float* glb = (const float*)d_in[19];
    const float* fw  = (const float*)d_in[20]; const float* fb  = (const float*)d_in[21];
    const float* lw  = (const float*)d_in[22]; const float* lb  = (const float*)d_in[23];
    const int* sparse_in = (const int*)d_in[24];
    const int* seq_in    = (const int*)d_in[25];
    const int* hist_in   = (const int*)d_in[26];
    float* out = (float*)d_out;
    float* dnn_ws = (float*)d_ws;   // B*184 floats = 12.06 MB

    hipLaunchKernelGGL(k1_fused, dim3(BB / 4), dim3(256), 0, stream,
                       dense, tables, seq_table, aw1, ab1, aw2, ab2, aw3, ab3,
                       gW, gU, gB, sparse_in, seq_in, hist_in, dnn_ws);
    hipLaunchKernelGGL(k2_mmoe, dim3(BB / BBT), dim3(256), 0, stream,
                       dnn_ws, ew1, eb1, ew2, eb2, gfw, gfb, glw, glb,
                       fw, fb, lw, lb, out);
}

// Round 8
// 528.507 us; speedup vs baseline: 1.2181x; 1.1027x over previous
//
#include <hip/hip_runtime.h>

#define BB 16384
#define TT 50
#define EMBD 16
#define NSP 8
#define NDD 8
#define VV 100000
#define DNN 184
#define NEGINF (-4294967295.0f)

typedef float f32x4 __attribute__((ext_vector_type(4)));
typedef short bf16x8 __attribute__((ext_vector_type(8)));

__device__ __forceinline__ float sigmoidf_(float x) { return 1.0f / (1.0f + __expf(-x)); }
__device__ __forceinline__ float tanhf_(float x) { return 1.0f - 2.0f / (__expf(2.0f * x) + 1.0f); }

__device__ __forceinline__ unsigned short f2bf(float x) {
    union { float f; unsigned u; } c; c.f = x;
    unsigned r = c.u + 0x7FFFu + ((c.u >> 16) & 1u);   // RNE
    return (unsigned short)(r >> 16);
}
__device__ __forceinline__ unsigned pack2(float lo, float hi) {
    return (unsigned)f2bf(lo) | ((unsigned)f2bf(hi) << 16);
}

// ---------------- K1: 2 waves/block, wave w owns b = blockIdx*2+w; DIN via MFMA ----------------
__global__ __launch_bounds__(128, 3) void k1_fused(
    const float* __restrict__ dense,
    const float* __restrict__ tables,
    const float* __restrict__ seq_table,
    const float* __restrict__ aw1, const float* __restrict__ ab1,
    const float* __restrict__ aw2, const float* __restrict__ ab2,
    const float* __restrict__ aw3, const float* __restrict__ ab3,
    const float* __restrict__ gW, const float* __restrict__ gU, const float* __restrict__ gB,
    const int* __restrict__ sparse_in, const int* __restrict__ seq_in, const int* __restrict__ hist_in,
    float* __restrict__ dnn_out)
{
    const int w = threadIdx.x >> 6;
    const int lane = threadIdx.x & 63;
    const int b = blockIdx.x * 2 + w;
    const int g = lane >> 4, r16 = lane & 15;

    __shared__ __align__(16) float histE[2][64][16];          // 8 KB
    __shared__ float maskL[2][64];
    __shared__ float qsh[2][16];
    __shared__ float dnnL[2][DNN];
    __shared__ float wsoft[2][64];
    __shared__ __align__(16) unsigned short attB[2][64][72];  // 18 KB; reused as h1-store

    // ---- staging ----
    if (lane < TT) {
        int hidx = hist_in[b * TT + lane];
        const float4* src = (const float4*)(tables + (size_t)hidx * EMBD);
        float4 a0 = src[0], a1 = src[1], a2 = src[2], a3 = src[3];
        *(float4*)&histE[w][lane][0]  = a0;
        *(float4*)&histE[w][lane][4]  = a1;
        *(float4*)&histE[w][lane][8]  = a2;
        *(float4*)&histE[w][lane][12] = a3;
        maskL[w][lane] = (hidx != 0) ? 1.0f : 0.0f;
    } else {
        float4 z = make_float4(0.f, 0.f, 0.f, 0.f);
        *(float4*)&histE[w][lane][0]  = z;
        *(float4*)&histE[w][lane][4]  = z;
        *(float4*)&histE[w][lane][8]  = z;
        *(float4*)&histE[w][lane][12] = z;
        maskL[w][lane] = 0.0f;
    }
    if (lane < EMBD) {
        int ti = sparse_in[b * NSP];
        qsh[w][lane] = tables[(size_t)ti * EMBD + lane];
    }
    if (lane < NDD) dnnL[w][lane] = dense[b * NDD + lane];
    for (int i = lane; i < NSP * EMBD; i += 64) {
        int s = i >> 4, j = i & 15;
        int idx = sparse_in[b * NSP + s];
        dnnL[w][NDD + i] = tables[((size_t)s * VV + idx) * EMBD + j];
    }
    {   // seq mean
        int gg = lane >> 4, j = lane & 15;
        float acc = 0.0f;
        for (int t = gg; t < TT; t += 4) {
            int idx = seq_in[b * TT + t];
            acc += seq_table[(size_t)idx * EMBD + j];
        }
        acc += __shfl_xor(acc, 16);
        acc += __shfl_xor(acc, 32);
        if (lane < EMBD) dnnL[w][NDD + NSP * EMBD + lane] = acc * (1.0f / TT);
    }
    __syncthreads();

    // ---- build MFMA weight fragments (lane-local; k-mapping = kc*32 + g*8 + j for BOTH A and B) ----
    bf16x8 a1f[4][2];   // w1^T A-frags: A[u=mt*16+r16][f=kc*32+g*8+j] = aw1[f][u]
    #pragma unroll
    for (int mt = 0; mt < 4; ++mt)
        #pragma unroll
        for (int kc = 0; kc < 2; ++kc)
            #pragma unroll
            for (int j = 0; j < 8; ++j)
                a1f[mt][kc][j] = (short)f2bf(aw1[(kc * 32 + g * 8 + j) * 64 + mt * 16 + r16]);
    bf16x8 a2f[2][2];   // w2^T A-frags: A[v=mt*16+r16][u=kc*32+g*8+j] = aw2[u][v]
    #pragma unroll
    for (int mt = 0; mt < 2; ++mt)
        #pragma unroll
        for (int kc = 0; kc < 2; ++kc)
            #pragma unroll
            for (int j = 0; j < 8; ++j)
                a2f[mt][kc][j] = (short)f2bf(aw2[(kc * 32 + g * 8 + j) * 32 + mt * 16 + r16]);

    // ---- build attB: row t = lane, f-layout [q|k|q-k|q*k] as bf16 ----
    {
        float qv[16], kv[16];
        #pragma unroll
        for (int j = 0; j < 16; ++j) { qv[j] = qsh[w][j]; kv[j] = histE[w][lane][j]; }
        unsigned short* rowp = &attB[w][lane][0];
        uint4 u;
        u.x = pack2(qv[0], qv[1]);   u.y = pack2(qv[2], qv[3]);
        u.z = pack2(qv[4], qv[5]);   u.w = pack2(qv[6], qv[7]);
        *(uint4*)&rowp[0] = u;
        u.x = pack2(qv[8], qv[9]);   u.y = pack2(qv[10], qv[11]);
        u.z = pack2(qv[12], qv[13]); u.w = pack2(qv[14], qv[15]);
        *(uint4*)&rowp[8] = u;
        u.x = pack2(kv[0], kv[1]);   u.y = pack2(kv[2], kv[3]);
        u.z = pack2(kv[4], kv[5]);   u.w = pack2(kv[6], kv[7]);
        *(uint4*)&rowp[16] = u;
        u.x = pack2(kv[8], kv[9]);   u.y = pack2(kv[10], kv[11]);
        u.z = pack2(kv[12], kv[13]); u.w = pack2(kv[14], kv[15]);
        *(uint4*)&rowp[24] = u;
        u.x = pack2(qv[0]-kv[0], qv[1]-kv[1]);   u.y = pack2(qv[2]-kv[2], qv[3]-kv[3]);
        u.z = pack2(qv[4]-kv[4], qv[5]-kv[5]);   u.w = pack2(qv[6]-kv[6], qv[7]-kv[7]);
        *(uint4*)&rowp[32] = u;
        u.x = pack2(qv[8]-kv[8], qv[9]-kv[9]);   u.y = pack2(qv[10]-kv[10], qv[11]-kv[11]);
        u.z = pack2(qv[12]-kv[12], qv[13]-kv[13]); u.w = pack2(qv[14]-kv[14], qv[15]-kv[15]);
        *(uint4*)&rowp[40] = u;
        u.x = pack2(qv[0]*kv[0], qv[1]*kv[1]);   u.y = pack2(qv[2]*kv[2], qv[3]*kv[3]);
        u.z = pack2(qv[4]*kv[4], qv[5]*kv[5]);   u.w = pack2(qv[6]*kv[6], qv[7]*kv[7]);
        *(uint4*)&rowp[48] = u;
        u.x = pack2(qv[8]*kv[8], qv[9]*kv[9]);   u.y = pack2(qv[10]*kv[10], qv[11]*kv[11]);
        u.z = pack2(qv[12]*kv[12], qv[13]*kv[13]); u.w = pack2(qv[14]*kv[14], qv[15]*kv[15]);
        *(uint4*)&rowp[56] = u;
    }
    __syncthreads();

    // ---- h1^T = w1^T @ att^T via MFMA; relu+bias; store bf16 back into attB as h1st[t][u] ----
    #pragma unroll
    for (int nt = 0; nt < 4; ++nt) {
        const unsigned short* rp = &attB[w][nt * 16 + r16][g * 8];
        bf16x8 b0 = *(const bf16x8*)(rp);        // f = 0..31 slice (this lane's 8)
        bf16x8 b1 = *(const bf16x8*)(rp + 32);   // f = 32..63 slice
        #pragma unroll
        for (int mt = 0; mt < 4; ++mt) {
            f32x4 acc = {0.f, 0.f, 0.f, 0.f};
            acc = __builtin_amdgcn_mfma_f32_16x16x32_bf16(a1f[mt][0], b0, acc, 0, 0, 0);
            acc = __builtin_amdgcn_mfma_f32_16x16x32_bf16(a1f[mt][1], b1, acc, 0, 0, 0);
            const float4 bia = *(const float4*)(ab1 + mt * 16 + g * 4);
            float v0 = fmaxf(acc[0] + bia.x, 0.0f);
            float v1 = fmaxf(acc[1] + bia.y, 0.0f);
            float v2 = fmaxf(acc[2] + bia.z, 0.0f);
            float v3 = fmaxf(acc[3] + bia.w, 0.0f);
            uint2 pw; pw.x = pack2(v0, v1); pw.y = pack2(v2, v3);
            *(uint2*)&attB[w][nt * 16 + r16][mt * 16 + g * 4] = pw;   // h1st[t][u]
        }
    }

    // ---- h2^T = w2^T @ h1 via MFMA; relu+bias; score = h2^T·w3 reduced over v ----
    float snt[4];
    #pragma unroll
    for (int nt = 0; nt < 4; ++nt) {
        const unsigned short* rp = &attB[w][nt * 16 + r16][g * 8];
        bf16x8 c0 = *(const bf16x8*)(rp);        // u = 0..31 slice
        bf16x8 c1 = *(const bf16x8*)(rp + 32);   // u = 32..63 slice
        float sp = 0.0f;
        #pragma unroll
        for (int mt = 0; mt < 2; ++mt) {
            f32x4 acc = {0.f, 0.f, 0.f, 0.f};
            acc = __builtin_amdgcn_mfma_f32_16x16x32_bf16(a2f[mt][0], c0, acc, 0, 0, 0);
            acc = __builtin_amdgcn_mfma_f32_16x16x32_bf16(a2f[mt][1], c1, acc, 0, 0, 0);
            const float4 bia = *(const float4*)(ab2 + mt * 16 + g * 4);
            const float4 w3v = *(const float4*)(aw3 + mt * 16 + g * 4);
            sp += fmaxf(acc[0] + bia.x, 0.0f) * w3v.x;
            sp += fmaxf(acc[1] + bia.y, 0.0f) * w3v.y;
            sp += fmaxf(acc[2] + bia.z, 0.0f) * w3v.z;
            sp += fmaxf(acc[3] + bia.w, 0.0f) * w3v.w;
        }
        sp += __shfl_xor(sp, 16);
        sp += __shfl_xor(sp, 32);
        snt[nt] = sp;          // score for t = nt*16 + r16 (valid on all lanes)
    }
    // lane l's score for t = l is snt[g] (t = g*16 + r16 = l)
    float score = (g == 0) ? snt[0] : (g == 1) ? snt[1] : (g == 2) ? snt[2] : snt[3];
    score += ab3[0];

    float mask = maskL[w][lane];
    score = (lane < TT && mask > 0.0f) ? score : NEGINF;
    float m = score;
    #pragma unroll
    for (int off = 32; off > 0; off >>= 1) m = fmaxf(m, __shfl_xor(m, off));
    float e = (lane < TT) ? __expf(score - m) : 0.0f;
    float ssum = e;
    #pragma unroll
    for (int off = 32; off > 0; off >>= 1) ssum += __shfl_xor(ssum, off);
    wsoft[w][lane] = e / ssum;
    __syncthreads();

    // din_out: all 64 lanes (g = t-group, r16 = emb)
    {
        float da = 0.0f;
        for (int t = g; t < TT; t += 4) da += wsoft[w][t] * histE[w][t][r16];
        da += __shfl_xor(da, 16);
        da += __shfl_xor(da, 32);
        if (lane < EMBD) dnnL[w][NDD + NSP * EMBD + EMBD + lane] = da;  // [152..167]
    }

    // ---- GRU: barrier-free, h state in lanes 0..15, units on lanes 0..47 ----
    float Wc[EMBD], Uc[EMBD], bi = 0.0f, br = 0.0f;
    if (lane < 48) {
        #pragma unroll
        for (int v = 0; v < EMBD; ++v) { Wc[v] = gW[v * 48 + lane]; Uc[v] = gU[v * 48 + lane]; }
        bi = gB[lane]; br = gB[48 + lane];
    }
    float hcur = 0.0f;
    for (int t = 0; t < TT; ++t) {
        float4 x0 = *(const float4*)&histE[w][t][0];
        float4 x1 = *(const float4*)&histE[w][t][4];
        float4 x2 = *(const float4*)&histE[w][t][8];
        float4 x3 = *(const float4*)&histE[w][t][12];
        float mt = maskL[w][t];
        float hv[16];
        #pragma unroll
        for (int v = 0; v < 16; ++v) hv[v] = __shfl(hcur, v);
        float xa = bi, rc = br;
        xa += x0.x*Wc[0] + x0.y*Wc[1] + x0.z*Wc[2] + x0.w*Wc[3];
        xa += x1.x*Wc[4] + x1.y*Wc[5] + x1.z*Wc[6] + x1.w*Wc[7];
        xa += x2.x*Wc[8] + x2.y*Wc[9] + x2.z*Wc[10] + x2.w*Wc[11];
        xa += x3.x*Wc[12] + x3.y*Wc[13] + x3.z*Wc[14] + x3.w*Wc[15];
        #pragma unroll
        for (int v = 0; v < 16; ++v) rc += hv[v] * Uc[v];
        float xr = __shfl(xa, lane + 16), xh = __shfl(xa, lane + 32);
        float rr = __shfl(rc, lane + 16), rh = __shfl(rc, lane + 32);
        float z  = sigmoidf_(xa + rc);
        float r  = sigmoidf_(xr + rr);
        float hh = tanhf_(xh + r * rh);
        float hnew = z * hcur + (1.0f - z) * hh;
        hcur = (mt > 0.0f) ? hnew : hcur;
    }
    if (lane < EMBD) dnnL[w][DNN - EMBD + lane] = hcur;   // [168..183]
    __syncthreads();

    for (int i = lane; i < DNN; i += 64)
        dnn_out[(size_t)b * DNN + i] = dnnL[w][i];
}

// ---------------- K2: MMOE + gates + heads, 8 batch rows per block (unchanged) ----------------
#define BBT 8
__global__ __launch_bounds__(256) void k2_mmoe(
    const float* __restrict__ dnn_in,
    const float* __restrict__ ew1, const float* __restrict__ eb1,
    const float* __restrict__ ew2, const float* __restrict__ eb2,
    const float* __restrict__ gfw, const float* __restrict__ gfb,
    const float* __restrict__ glw, const float* __restrict__ glb,
    const float* __restrict__ fw, const float* __restrict__ fb,
    const float* __restrict__ lw, const float* __restrict__ lb,
    float* __restrict__ out)
{
    const int tid = threadIdx.x;
    const int b0 = blockIdx.x * BBT;

    __shared__ float dlds[BBT * DNN];
    __shared__ float h1L[BBT][512];
    __shared__ float h2L[BBT][256];
    __shared__ float gateL[BBT][8];

    {
        const float* drow = dnn_in + (size_t)b0 * DNN;
        for (int i = tid; i < BBT * DNN; i += 256) dlds[i] = drow[i];
    }
    __syncthreads();

    {
        int col0 = tid;
        int e0 = col0 >> 7, i0 = col0 & 127;
        const float* wp0 = ew1 + (size_t)e0 * DNN * 128 + i0;
        const float* wp1 = ew1 + (size_t)(e0 + 2) * DNN * 128 + i0;
        float acc0[BBT], acc1[BBT];
        float bias0 = eb1[col0], bias1 = eb1[col0 + 256];
        #pragma unroll
        for (int bb = 0; bb < BBT; ++bb) { acc0[bb] = bias0; acc1[bb] = bias1; }
        for (int d = 0; d < DNN; d += 4) {
            float w00 = wp0[(size_t)(d + 0) * 128], w01 = wp0[(size_t)(d + 1) * 128];
            float w02 = wp0[(size_t)(d + 2) * 128], w03 = wp0[(size_t)(d + 3) * 128];
            float w10 = wp1[(size_t)(d + 0) * 128], w11 = wp1[(size_t)(d + 1) * 128];
            float w12 = wp1[(size_t)(d + 2) * 128], w13 = wp1[(size_t)(d + 3) * 128];
            #pragma unroll
            for (int bb = 0; bb < BBT; ++bb) {
                const float4 h4 = *(const float4*)&dlds[bb * DNN + d];
                acc0[bb] += h4.x * w00 + h4.y * w01 + h4.z * w02 + h4.w * w03;
                acc1[bb] += h4.x * w10 + h4.y * w11 + h4.z * w12 + h4.w * w13;
            }
        }
        #pragma unroll
        for (int bb = 0; bb < BBT; ++bb) {
            h1L[bb][col0]       = fmaxf(acc0[bb], 0.0f);
            h1L[bb][col0 + 256] = fmaxf(acc1[bb], 0.0f);
        }
    }

    if (tid < 64) {
        int bb = tid >> 3, which = (tid >> 2) & 1, eidx = tid & 3;
        const float* gw = which ? glw : gfw;
        float acc = which ? glb[eidx] : gfb[eidx];
        for (int d = 0; d < DNN; ++d) acc += dlds[bb * DNN + d] * gw[d * 4 + eidx];
        gateL[bb][which * 4 + eidx] = acc;
    }
    __syncthreads();

    if (tid < 16) {
        int bb = tid >> 1, which = tid & 1;
        float l0 = gateL[bb][which * 4 + 0], l1 = gateL[bb][which * 4 + 1];
        float l2 = gateL[bb][which * 4 + 2], l3 = gateL[bb][which * 4 + 3];
        float mm = fmaxf(fmaxf(l0, l1), fmaxf(l2, l3));
        float e0 = __expf(l0 - mm), e1 = __expf(l1 - mm), e2 = __expf(l2 - mm), e3 = __expf(l3 - mm);
        float ss = e0 + e1 + e2 + e3;
        gateL[bb][which * 4 + 0] = e0 / ss; gateL[bb][which * 4 + 1] = e1 / ss;
        gateL[bb][which * 4 + 2] = e2 / ss; gateL[bb][which * 4 + 3] = e3 / ss;
    }

    {
        int col = tid;
        int eidx = col >> 6, i = col & 63;
        const float* wp = ew2 + (size_t)eidx * 128 * 64 + i;
        float acc[BBT];
        float bias = eb2[col];
        #pragma unroll
        for (int bb = 0; bb < BBT; ++bb) acc[bb] = bias;
        for (int d = 0; d < 128; d += 4) {
            float w0 = wp[(d + 0) * 64], w1v = wp[(d + 1) * 64];
            float w2v = wp[(d + 2) * 64], w3v = wp[(d + 3) * 64];
            #pragma unroll
            for (int bb = 0; bb < BBT; ++bb) {
                const float4 h4 = *(const float4*)&h1L[bb][eidx * 128 + d];
                acc[bb] += h4.x * w0 + h4.y * w1v + h4.z * w2v + h4.w * w3v;
            }
        }
        #pragma unroll
        for (int bb = 0; bb < BBT; ++bb) h2L[bb][col] = fmaxf(acc[bb], 0.0f);
    }
    __syncthreads();

    {
        int wv = tid >> 6, lane = tid & 63;
        for (int it = 0; it < 2; ++it) {
            int bb = wv * 2 + it;
            float h0 = h2L[bb][lane], h1v = h2L[bb][64 + lane];
            float h2v = h2L[bb][128 + lane], h3v = h2L[bb][192 + lane];
            float fin = gateL[bb][0] * h0 + gateL[bb][1] * h1v + gateL[bb][2] * h2v + gateL[bb][3] * h3v;
            float lik = gateL[bb][4] * h0 + gateL[bb][5] * h1v + gateL[bb][6] * h2v + gateL[bb][7] * h3v;
            float pf = fin * fw[lane];
            float pl = lik * lw[lane];
            #pragma unroll
            for (int off = 32; off > 0; off >>= 1) {
                pf += __shfl_xor(pf, off);
                pl += __shfl_xor(pl, off);
            }
            if (lane == 0) {
                out[b0 + bb]      = sigmoidf_(pf + fb[0]);
                out[BB + b0 + bb] = sigmoidf_(pl + lb[0]);
            }
        }
    }
}

extern "C" void kernel_launch(void* const* d_in, const int* in_sizes, int n_in,
                              void* d_out, int out_size, void* d_ws, size_t ws_size,
                              hipStream_t stream)
{
    const float* dense     = (const float*)d_in[0];
    const float* tables    = (const float*)d_in[1];
    const float* seq_table = (const float*)d_in[2];
    const float* aw1 = (const float*)d_in[3];  const float* ab1 = (const float*)d_in[4];
    const float* aw2 = (const float*)d_in[5];  const float* ab2 = (const float*)d_in[6];
    const float* aw3 = (const float*)d_in[7];  const float* ab3 = (const float*)d_in[8];
    const float* gW  = (const float*)d_in[9];  const float* gU  = (const float*)d_in[10];
    const float* gB  = (const float*)d_in[11];
    const float* ew1 = (const float*)d_in[12]; const float* eb1 = (const float*)d_in[13];
    const float* ew2 = (const float*)d_in[14]; const float* eb2 = (const float*)d_in[15];
    const float* gfw = (const float*)d_in[16]; const float* gfb = (const float*)d_in[17];
    const float* glw = (const float*)d_in[18]; const float* glb = (const float*)d_in[19];
    const float* fw  = (const float*)d_in[20]; const float* fb  = (const float*)d_in[21];
    const float* lw  = (const float*)d_in[22]; const float* lb  = (const float*)d_in[23];
    const int* sparse_in = (const int*)d_in[24];
    const int* seq_in    = (const int*)d_in[25];
    const int* hist_in   = (const int*)d_in[26];
    float* out = (float*)d_out;
    float* dnn_ws = (float*)d_ws;   // B*184 floats = 12.06 MB

    hipLaunchKernelGGL(k1_fused, dim3(BB / 2), dim3(128), 0, stream,
                       dense, tables, seq_table, aw1, ab1, aw2, ab2, aw3, ab3,
                       gW, gU, gB, sparse_in, seq_in, hist_in, dnn_ws);
    hipLaunchKernelGGL(k2_mmoe, dim3(BB / BBT), dim3(256), 0, stream,
                       dnn_ws, ew1, eb1, ew2, eb2, gfw, gfb, glw, glb,
                       fw, fb, lw, lb, out);
}

// Round 11
// 478.224 us; speedup vs baseline: 1.3462x; 1.1051x over previous
//
#include <hip/hip_runtime.h>

#define BB 16384
#define TT 50
#define EMBD 16
#define NSP 8
#define NDD 8
#define VV 100000
#define DNN 184
#define NEGINF (-4294967295.0f)

typedef float f32x4 __attribute__((ext_vector_type(4)));
typedef short bf16x8 __attribute__((ext_vector_type(8)));

__device__ __forceinline__ float sigmoidf_(float x) { return 1.0f / (1.0f + __expf(-x)); }
__device__ __forceinline__ float tanhf_(float x) { return 1.0f - 2.0f / (__expf(2.0f * x) + 1.0f); }

__device__ __forceinline__ unsigned short f2bf(float x) {
    union { float f; unsigned u; } c; c.f = x;
    unsigned r = c.u + 0x7FFFu + ((c.u >> 16) & 1u);   // RNE
    return (unsigned short)(r >> 16);
}
__device__ __forceinline__ unsigned pack2(float lo, float hi) {
    return (unsigned)f2bf(lo) | ((unsigned)f2bf(hi) << 16);
}

// ---------------- kconv: transpose+convert MMOE weights to bf16 in ws ----------------
// w1t[n][k] (pitch 192, k>=184 zero) = ew1[n>>7][k][n&127];  w2t[e*64+n2][k] (pitch 128) = ew2[e][k][n2]
__global__ __launch_bounds__(192) void kconv(
    const float* __restrict__ ew1, const float* __restrict__ ew2,
    unsigned short* __restrict__ w1t, unsigned short* __restrict__ w2t)
{
    const int bid = blockIdx.x, tid = threadIdx.x;
    if (bid < 512) {
        float v = 0.0f;
        if (tid < 184) v = ew1[(size_t)(bid >> 7) * 184 * 128 + (size_t)tid * 128 + (bid & 127)];
        w1t[bid * 192 + tid] = f2bf(v);
    } else {
        const int e = (bid - 512) >> 6, n2 = (bid - 512) & 63;
        if (tid < 128)
            w2t[(size_t)(e * 64 + n2) * 128 + tid] = f2bf(ew2[(size_t)e * 128 * 64 + tid * 64 + n2]);
    }
}

// ---------------- K1: 2 waves/block (R8-validated); DIN via MFMA ----------------
__global__ __launch_bounds__(128, 3) void k1_fused(
    const float* __restrict__ dense,
    const float* __restrict__ tables,
    const float* __restrict__ seq_table,
    const float* __restrict__ aw1, const float* __restrict__ ab1,
    const float* __restrict__ aw2, const float* __restrict__ ab2,
    const float* __restrict__ aw3, const float* __restrict__ ab3,
    const float* __restrict__ gW, const float* __restrict__ gU, const float* __restrict__ gB,
    const int* __restrict__ sparse_in, const int* __restrict__ seq_in, const int* __restrict__ hist_in,
    float* __restrict__ dnn_out)
{
    const int w = threadIdx.x >> 6;
    const int lane = threadIdx.x & 63;
    const int b = blockIdx.x * 2 + w;
    const int g = lane >> 4, r16 = lane & 15;

    __shared__ __align__(16) float histE[2][64][16];
    __shared__ float maskL[2][64];
    __shared__ float qsh[2][16];
    __shared__ float dnnL[2][DNN];
    __shared__ float wsoft[2][64];
    __shared__ __align__(16) unsigned short attB[2][64][72];

    if (lane < TT) {
        int hidx = hist_in[b * TT + lane];
        const float4* src = (const float4*)(tables + (size_t)hidx * EMBD);
        float4 a0 = src[0], a1 = src[1], a2 = src[2], a3 = src[3];
        *(float4*)&histE[w][lane][0]  = a0;
        *(float4*)&histE[w][lane][4]  = a1;
        *(float4*)&histE[w][lane][8]  = a2;
        *(float4*)&histE[w][lane][12] = a3;
        maskL[w][lane] = (hidx != 0) ? 1.0f : 0.0f;
    } else {
        float4 z = make_float4(0.f, 0.f, 0.f, 0.f);
        *(float4*)&histE[w][lane][0]  = z;
        *(float4*)&histE[w][lane][4]  = z;
        *(float4*)&histE[w][lane][8]  = z;
        *(float4*)&histE[w][lane][12] = z;
        maskL[w][lane] = 0.0f;
    }
    if (lane < EMBD) {
        int ti = sparse_in[b * NSP];
        qsh[w][lane] = tables[(size_t)ti * EMBD + lane];
    }
    if (lane < NDD) dnnL[w][lane] = dense[b * NDD + lane];
    for (int i = lane; i < NSP * EMBD; i += 64) {
        int s = i >> 4, j = i & 15;
        int idx = sparse_in[b * NSP + s];
        dnnL[w][NDD + i] = tables[((size_t)s * VV + idx) * EMBD + j];
    }
    {
        int gg = lane >> 4, j = lane & 15;
        float acc = 0.0f;
        for (int t = gg; t < TT; t += 4) {
            int idx = seq_in[b * TT + t];
            acc += seq_table[(size_t)idx * EMBD + j];
        }
        acc += __shfl_xor(acc, 16);
        acc += __shfl_xor(acc, 32);
        if (lane < EMBD) dnnL[w][NDD + NSP * EMBD + lane] = acc * (1.0f / TT);
    }
    __syncthreads();

    bf16x8 a1f[4][2];
    #pragma unroll
    for (int mt = 0; mt < 4; ++mt)
        #pragma unroll
        for (int kc = 0; kc < 2; ++kc)
            #pragma unroll
            for (int j = 0; j < 8; ++j)
                a1f[mt][kc][j] = (short)f2bf(aw1[(kc * 32 + g * 8 + j) * 64 + mt * 16 + r16]);
    bf16x8 a2f[2][2];
    #pragma unroll
    for (int mt = 0; mt < 2; ++mt)
        #pragma unroll
        for (int kc = 0; kc < 2; ++kc)
            #pragma unroll
            for (int j = 0; j < 8; ++j)
                a2f[mt][kc][j] = (short)f2bf(aw2[(kc * 32 + g * 8 + j) * 32 + mt * 16 + r16]);

    {
        float qv[16], kv[16];
        #pragma unroll
        for (int j = 0; j < 16; ++j) { qv[j] = qsh[w][j]; kv[j] = histE[w][lane][j]; }
        unsigned short* rowp = &attB[w][lane][0];
        uint4 u;
        u.x = pack2(qv[0], qv[1]);   u.y = pack2(qv[2], qv[3]);
        u.z = pack2(qv[4], qv[5]);   u.w = pack2(qv[6], qv[7]);
        *(uint4*)&rowp[0] = u;
        u.x = pack2(qv[8], qv[9]);   u.y = pack2(qv[10], qv[11]);
        u.z = pack2(qv[12], qv[13]); u.w = pack2(qv[14], qv[15]);
        *(uint4*)&rowp[8] = u;
        u.x = pack2(kv[0], kv[1]);   u.y = pack2(kv[2], kv[3]);
        u.z = pack2(kv[4], kv[5]);   u.w = pack2(kv[6], kv[7]);
        *(uint4*)&rowp[16] = u;
        u.x = pack2(kv[8], kv[9]);   u.y = pack2(kv[10], kv[11]);
        u.z = pack2(kv[12], kv[13]); u.w = pack2(kv[14], kv[15]);
        *(uint4*)&rowp[24] = u;
        u.x = pack2(qv[0]-kv[0], qv[1]-kv[1]);   u.y = pack2(qv[2]-kv[2], qv[3]-kv[3]);
        u.z = pack2(qv[4]-kv[4], qv[5]-kv[5]);   u.w = pack2(qv[6]-kv[6], qv[7]-kv[7]);
        *(uint4*)&rowp[32] = u;
        u.x = pack2(qv[8]-kv[8], qv[9]-kv[9]);   u.y = pack2(qv[10]-kv[10], qv[11]-kv[11]);
        u.z = pack2(qv[12]-kv[12], qv[13]-kv[13]); u.w = pack2(qv[14]-kv[14], qv[15]-kv[15]);
        *(uint4*)&rowp[40] = u;
        u.x = pack2(qv[0]*kv[0], qv[1]*kv[1]);   u.y = pack2(qv[2]*kv[2], qv[3]*kv[3]);
        u.z = pack2(qv[4]*kv[4], qv[5]*kv[5]);   u.w = pack2(qv[6]*kv[6], qv[7]*kv[7]);
        *(uint4*)&rowp[48] = u;
        u.x = pack2(qv[8]*kv[8], qv[9]*kv[9]);   u.y = pack2(qv[10]*kv[10], qv[11]*kv[11]);
        u.z = pack2(qv[12]*kv[12], qv[13]*kv[13]); u.w = pack2(qv[14]*kv[14], qv[15]*kv[15]);
        *(uint4*)&rowp[56] = u;
    }
    __syncthreads();

    #pragma unroll
    for (int nt = 0; nt < 4; ++nt) {
        const unsigned short* rp = &attB[w][nt * 16 + r16][g * 8];
        bf16x8 b0 = *(const bf16x8*)(rp);
        bf16x8 b1 = *(const bf16x8*)(rp + 32);
        #pragma unroll
        for (int mt = 0; mt < 4; ++mt) {
            f32x4 acc = {0.f, 0.f, 0.f, 0.f};
            acc = __builtin_amdgcn_mfma_f32_16x16x32_bf16(a1f[mt][0], b0, acc, 0, 0, 0);
            acc = __builtin_amdgcn_mfma_f32_16x16x32_bf16(a1f[mt][1], b1, acc, 0, 0, 0);
            const float4 bia = *(const float4*)(ab1 + mt * 16 + g * 4);
            float v0 = fmaxf(acc[0] + bia.x, 0.0f);
            float v1 = fmaxf(acc[1] + bia.y, 0.0f);
            float v2 = fmaxf(acc[2] + bia.z, 0.0f);
            float v3 = fmaxf(acc[3] + bia.w, 0.0f);
            uint2 pw; pw.x = pack2(v0, v1); pw.y = pack2(v2, v3);
            *(uint2*)&attB[w][nt * 16 + r16][mt * 16 + g * 4] = pw;
        }
    }

    float snt[4];
    #pragma unroll
    for (int nt = 0; nt < 4; ++nt) {
        const unsigned short* rp = &attB[w][nt * 16 + r16][g * 8];
        bf16x8 c0 = *(const bf16x8*)(rp);
        bf16x8 c1 = *(const bf16x8*)(rp + 32);
        float sp = 0.0f;
        #pragma unroll
        for (int mt = 0; mt < 2; ++mt) {
            f32x4 acc = {0.f, 0.f, 0.f, 0.f};
            acc = __builtin_amdgcn_mfma_f32_16x16x32_bf16(a2f[mt][0], c0, acc, 0, 0, 0);
            acc = __builtin_amdgcn_mfma_f32_16x16x32_bf16(a2f[mt][1], c1, acc, 0, 0, 0);
            const float4 bia = *(const float4*)(ab2 + mt * 16 + g * 4);
            const float4 w3v = *(const float4*)(aw3 + mt * 16 + g * 4);
            sp += fmaxf(acc[0] + bia.x, 0.0f) * w3v.x;
            sp += fmaxf(acc[1] + bia.y, 0.0f) * w3v.y;
            sp += fmaxf(acc[2] + bia.z, 0.0f) * w3v.z;
            sp += fmaxf(acc[3] + bia.w, 0.0f) * w3v.w;
        }
        sp += __shfl_xor(sp, 16);
        sp += __shfl_xor(sp, 32);
        snt[nt] = sp;
    }
    float score = (g == 0) ? snt[0] : (g == 1) ? snt[1] : (g == 2) ? snt[2] : snt[3];
    score += ab3[0];

    float mask = maskL[w][lane];
    score = (lane < TT && mask > 0.0f) ? score : NEGINF;
    float m = score;
    #pragma unroll
    for (int off = 32; off > 0; off >>= 1) m = fmaxf(m, __shfl_xor(m, off));
    float e = (lane < TT) ? __expf(score - m) : 0.0f;
    float ssum = e;
    #pragma unroll
    for (int off = 32; off > 0; off >>= 1) ssum += __shfl_xor(ssum, off);
    wsoft[w][lane] = e / ssum;
    __syncthreads();

    {
        float da = 0.0f;
        for (int t = g; t < TT; t += 4) da += wsoft[w][t] * histE[w][t][r16];
        da += __shfl_xor(da, 16);
        da += __shfl_xor(da, 32);
        if (lane < EMBD) dnnL[w][NDD + NSP * EMBD + EMBD + lane] = da;
    }

    float Wc[EMBD], Uc[EMBD], bi = 0.0f, br = 0.0f;
    if (lane < 48) {
        #pragma unroll
        for (int v = 0; v < EMBD; ++v) { Wc[v] = gW[v * 48 + lane]; Uc[v] = gU[v * 48 + lane]; }
        bi = gB[lane]; br = gB[48 + lane];
    }
    float hcur = 0.0f;
    for (int t = 0; t < TT; ++t) {
        float4 x0 = *(const float4*)&histE[w][t][0];
        float4 x1 = *(const float4*)&histE[w][t][4];
        float4 x2 = *(const float4*)&histE[w][t][8];
        float4 x3 = *(const float4*)&histE[w][t][12];
        float mt = maskL[w][t];
        float hv[16];
        #pragma unroll
        for (int v = 0; v < 16; ++v) hv[v] = __shfl(hcur, v);
        float xa = bi, rc = br;
        xa += x0.x*Wc[0] + x0.y*Wc[1] + x0.z*Wc[2] + x0.w*Wc[3];
        xa += x1.x*Wc[4] + x1.y*Wc[5] + x1.z*Wc[6] + x1.w*Wc[7];
        xa += x2.x*Wc[8] + x2.y*Wc[9] + x2.z*Wc[10] + x2.w*Wc[11];
        xa += x3.x*Wc[12] + x3.y*Wc[13] + x3.z*Wc[14] + x3.w*Wc[15];
        #pragma unroll
        for (int v = 0; v < 16; ++v) rc += hv[v] * Uc[v];
        float xr = __shfl(xa, lane + 16), xh = __shfl(xa, lane + 32);
        float rr = __shfl(rc, lane + 16), rh = __shfl(rc, lane + 32);
        float z  = sigmoidf_(xa + rc);
        float r  = sigmoidf_(xr + rr);
        float hh = tanhf_(xh + r * rh);
        float hnew = z * hcur + (1.0f - z) * hh;
        hcur = (mt > 0.0f) ? hnew : hcur;
    }
    if (lane < EMBD) dnnL[w][DNN - EMBD + lane] = hcur;
    __syncthreads();

    for (int i = lane; i < DNN; i += 64)
        dnn_out[(size_t)b * DNN + i] = dnnL[w][i];
}

// ---------------- K2: MMOE via MFMA; 32 b-rows/block, 4 waves ----------------
#define K2B 32
__global__ __launch_bounds__(256) void k2_mfma(
    const float* __restrict__ dnn_in,
    const unsigned short* __restrict__ w1t, const unsigned short* __restrict__ w2t,
    const float* __restrict__ eb1, const float* __restrict__ eb2,
    const float* __restrict__ gfw, const float* __restrict__ gfb,
    const float* __restrict__ glw, const float* __restrict__ glb,
    const float* __restrict__ fw, const float* __restrict__ fb,
    const float* __restrict__ lw, const float* __restrict__ lb,
    float* __restrict__ out)
{
    const int tid = threadIdx.x;
    const int b0 = blockIdx.x * K2B;
    const int wv = tid >> 6, lane = tid & 63, g = lane >> 4, r16 = lane & 15;
    const int rt = wv >> 1, nh = wv & 1;

    __shared__ __align__(16) unsigned short dldsb[K2B][208];  // 13 KB bf16 dnn, k>=184 zero
    __shared__ __align__(16) unsigned short h1b[K2B][520];    // 32.5 KB bf16 h1
    __shared__ float gateL[K2B][8];
    __shared__ float part[2][2][16][2];                       // [rt][nh][b16][head]

    // stage dnn -> bf16 LDS (8 threads/row, 23 cols each) + zero pad
    {
        const int row = tid >> 3, c8 = tid & 7;
        const float* src = dnn_in + (size_t)(b0 + row) * DNN + c8 * 23;
        unsigned short* dst = &dldsb[row][c8 * 23];
        #pragma unroll
        for (int c = 0; c < 23; ++c) dst[c] = f2bf(src[c]);
        #pragma unroll
        for (int c = 0; c < 3; ++c) dldsb[row][184 + c8 * 3 + c] = 0;
    }
    // gate logits f32 (one per thread: 32 rows x 2 gates x 4 experts)
    {
        const int bb = tid >> 3, which = (tid >> 2) & 1, e = tid & 3;
        const float* gw = which ? glw : gfw;
        float acc = which ? glb[e] : gfb[e];
        const float* dr = dnn_in + (size_t)(b0 + bb) * DNN;
        for (int d = 0; d < DNN; ++d) acc += dr[d] * gw[d * 4 + e];
        gateL[bb][which * 4 + e] = acc;
    }
    __syncthreads();

    // wave0: softmax gates (visible to all after the h1->h2 barrier)
    if (tid < 64) {
        const int bb = tid >> 1, which = tid & 1;
        float l0 = gateL[bb][which*4+0], l1 = gateL[bb][which*4+1];
        float l2 = gateL[bb][which*4+2], l3 = gateL[bb][which*4+3];
        float mm = fmaxf(fmaxf(l0, l1), fmaxf(l2, l3));
        float e0 = __expf(l0-mm), e1 = __expf(l1-mm), e2 = __expf(l2-mm), e3 = __expf(l3-mm);
        float ss = e0 + e1 + e2 + e3;
        gateL[bb][which*4+0] = e0/ss; gateL[bb][which*4+1] = e1/ss;
        gateL[bb][which*4+2] = e2/ss; gateL[bb][which*4+3] = e3/ss;
    }

    // h1: wave (rt, nh): rows rt*16..+16, n-tiles nh*16..+16
    {
        bf16x8 af[6];
        #pragma unroll
        for (int kk = 0; kk < 6; ++kk)
            af[kk] = *(const bf16x8*)&dldsb[rt * 16 + r16][kk * 32 + g * 8];
        for (int nt = nh * 16; nt < nh * 16 + 16; ++nt) {
            f32x4 acc = {0.f, 0.f, 0.f, 0.f};
            const unsigned short* wp = w1t + (size_t)(nt * 16 + r16) * 192 + g * 8;
            #pragma unroll
            for (int kk = 0; kk < 6; ++kk) {
                bf16x8 bf = *(const bf16x8*)(wp + kk * 32);
                acc = __builtin_amdgcn_mfma_f32_16x16x32_bf16(af[kk], bf, acc, 0, 0, 0);
            }
            const float eb1v = eb1[nt * 16 + r16];
            #pragma unroll
            for (int reg = 0; reg < 4; ++reg)
                h1b[rt * 16 + g * 4 + reg][nt * 16 + r16] = f2bf(fmaxf(acc[reg] + eb1v, 0.0f));
        }
    }
    __syncthreads();

    // h2 + gated head accumulation: wave (rt, nh): experts {nh*2, nh*2+1}
    {
        float accF[4] = {0.f,0.f,0.f,0.f}, accL[4] = {0.f,0.f,0.f,0.f};
        #pragma unroll
        for (int eh = 0; eh < 2; ++eh) {
            const int e = nh * 2 + eh;
            bf16x8 af2[4];
            #pragma unroll
            for (int kk = 0; kk < 4; ++kk)
                af2[kk] = *(const bf16x8*)&h1b[rt * 16 + r16][e * 128 + kk * 32 + g * 8];
            float gF[4], gL[4];
            #pragma unroll
            for (int reg = 0; reg < 4; ++reg) {
                gF[reg] = gateL[rt * 16 + g * 4 + reg][e];
                gL[reg] = gateL[rt * 16 + g * 4 + reg][4 + e];
            }
            #pragma unroll
            for (int i16 = 0; i16 < 4; ++i16) {
                f32x4 acc = {0.f, 0.f, 0.f, 0.f};
                const unsigned short* wp = w2t + (size_t)(e * 64 + i16 * 16 + r16) * 128 + g * 8;
                #pragma unroll
                for (int kk = 0; kk < 4; ++kk) {
                    bf16x8 bf = *(const bf16x8*)(wp + kk * 32);
                    acc = __builtin_amdgcn_mfma_f32_16x16x32_bf16(af2[kk], bf, acc, 0, 0, 0);
                }
                const float eb2v = eb2[e * 64 + i16 * 16 + r16];
                const float fwv = fw[i16 * 16 + r16], lwv = lw[i16 * 16 + r16];
                #pragma unroll
                for (int reg = 0; reg < 4; ++reg) {
                    float h2v = fmaxf(acc[reg] + eb2v, 0.0f);
                    accF[reg] += gF[reg] * h2v * fwv;
                    accL[reg] += gL[reg] * h2v * lwv;
                }
            }
        }
        #pragma unroll
        for (int off = 1; off < 16; off <<= 1) {
            #pragma unroll
            for (int reg = 0; reg < 4; ++reg) {
                accF[reg] += __shfl_xor(accF[reg], off);
                accL[reg] += __shfl_xor(accL[reg], off);
            }
        }
        if (r16 == 0) {
            #pragma unroll
            for (int reg = 0; reg < 4; ++reg) {
                part[rt][nh][g * 4 + reg][0] = accF[reg];
                part[rt][nh][g * 4 + reg][1] = accL[reg];
            }
        }
    }
    __syncthreads();

    if (tid < 64) {
        const int bl = tid & 31, head = tid >> 5;
        float v = part[bl >> 4][0][bl & 15][head] + part[bl >> 4][1][bl & 15][head];
        if (head == 0) out[b0 + bl]      = sigmoidf_(v + fb[0]);
        else           out[BB + b0 + bl] = sigmoidf_(v + lb[0]);
    }
}

extern "C" void kernel_launch(void* const* d_in, const int* in_sizes, int n_in,
                              void* d_out, int out_size, void* d_ws, size_t ws_size,
                              hipStream_t stream)
{
    const float* dense     = (const float*)d_in[0];
    const float* tables    = (const float*)d_in[1];
    const float* seq_table = (const float*)d_in[2];
    const float* aw1 = (const float*)d_in[3];  const float* ab1 = (const float*)d_in[4];
    const float* aw2 = (const float*)d_in[5];  const float* ab2 = (const float*)d_in[6];
    const float* aw3 = (const float*)d_in[7];  const float* ab3 = (const float*)d_in[8];
    const float* gW  = (const float*)d_in[9];  const float* gU  = (const float*)d_in[10];
    const float* gB  = (const float*)d_in[11];
    const float* ew1 = (const float*)d_in[12]; const float* eb1 = (const float*)d_in[13];
    const float* ew2 = (const float*)d_in[14]; const float* eb2 = (const float*)d_in[15];
    const float* gfw = (const float*)d_in[16]; const float* gfb = (const float*)d_in[17];
    const float* glw = (const float*)d_in[18]; const float* glb = (const float*)d_in[19];
    const float* fw  = (const float*)d_in[20]; const float* fb  = (const float*)d_in[21];
    const float* lw  = (const float*)d_in[22]; const float* lb  = (const float*)d_in[23];
    const int* sparse_in = (const int*)d_in[24];
    const int* seq_in    = (const int*)d_in[25];
    const int* hist_in   = (const int*)d_in[26];
    float* out = (float*)d_out;

    // ws layout: dnn f32 [B*184] | w1t bf16 [512*192] | w2t bf16 [256*128]
    float* dnn_ws = (float*)d_ws;                                    // 12,058,624 B
    unsigned short* w1t = (unsigned short*)((char*)d_ws + (size_t)BB * DNN * 4);
    unsigned short* w2t = w1t + 512 * 192;

    hipLaunchKernelGGL(kconv, dim3(512 + 256), dim3(192), 0, stream, ew1, ew2, w1t, w2t);
    hipLaunchKernelGGL(k1_fused, dim3(BB / 2), dim3(128), 0, stream,
                       dense, tables, seq_table, aw1, ab1, aw2, ab2, aw3, ab3,
                       gW, gU, gB, sparse_in, seq_in, hist_in, dnn_ws);
    hipLaunchKernelGGL(k2_mfma, dim3(BB / K2B), dim3(256), 0, stream,
                       dnn_ws, w1t, w2t, eb1, eb2, gfw, gfb, glw, glb,
                       fw, fb, lw, lb, out);
}